// Round 10
// baseline (156.939 us; speedup 1.0000x reference)
//
#include <hip/hip_runtime.h>
#include <math.h>

// (B,C,H,W) = (16,64,256,256)
// out[b,d,hw] = relu( rrelu( sum_c mix[d,c]*softmax_c(x)[b,c,hw] + bias[d] ) + 0.1*x[b,d,hw] )
#define HWSZ 65536

typedef __bf16 bf16x8 __attribute__((ext_vector_type(8)));
typedef __bf16 bf16x4 __attribute__((ext_vector_type(4)));
typedef float f32x4 __attribute__((ext_vector_type(4)));

__global__ __launch_bounds__(256) void cvt_mix_kernel(const float* __restrict__ mix,
                                                      __bf16* __restrict__ mixb) {
    int i = blockIdx.x * 256 + threadIdx.x;   // 4096 elements
    mixb[i] = (__bf16)mix[i];
}

__global__ __launch_bounds__(256, 5) void fused_kernel(
    const float* __restrict__ x, const __bf16* __restrict__ mixb,
    const float* __restrict__ bias, float* __restrict__ out)
{
    // per-wave 64x64 bf16 s-tile, [pixel][channel], 16B-granule XOR swizzle.
    // Waves never touch each other's slice -> no __syncthreads anywhere.
    __shared__ __bf16 sT[4][64 * 64];
    const int tid  = threadIdx.x;
    const int wid  = tid >> 6;
    const int lane = tid & 63;

    // T1: XCD-aware bijective block swizzle. Dispatch round-robins blocks over
    // 8 XCDs; remap so each XCD works a CONTIGUOUS pixel span (DRAM row locality
    // + full L2-line use). 4096 % 8 == 0 -> bijective.
    const int bid = blockIdx.x;
    const int swz = (bid & 7) * 512 + (bid >> 3);

    const int waveg = swz * 4 + wid;              // 16384 waves
    const int b   = waveg >> 10;
    const int hw0 = (waveg & 1023) << 6;
    const size_t ibase = (size_t)b * (64 * HWSZ) + hw0;

    const float LOG2E = 1.44269504088896340736f;
    const float LN2   = 0.69314718055994530942f;

    // ---- phase 1: channel softmax for pixel hw0+lane ----
    const float* xp = x + ibase + lane;
    float e[64];
#pragma unroll
    for (int c = 0; c < 64; ++c) e[c] = xp[(size_t)c << 16];   // coalesced 256B/instr

    float m0 = e[0], m1 = e[1], m2 = e[2], m3 = e[3];
#pragma unroll
    for (int c = 4; c < 64; c += 4) {
        m0 = fmaxf(m0, e[c]);     m1 = fmaxf(m1, e[c + 1]);
        m2 = fmaxf(m2, e[c + 2]); m3 = fmaxf(m3, e[c + 3]);
    }
    const float m = fmaxf(fmaxf(m0, m1), fmaxf(m2, m3));

    float s0 = 0.f, s1 = 0.f, s2 = 0.f, s3 = 0.f;
#pragma unroll
    for (int c = 0; c < 64; c += 4) {
        e[c]     = __builtin_exp2f((e[c]     - m) * LOG2E); s0 += e[c];
        e[c + 1] = __builtin_exp2f((e[c + 1] - m) * LOG2E); s1 += e[c + 1];
        e[c + 2] = __builtin_exp2f((e[c + 2] - m) * LOG2E); s2 += e[c + 2];
        e[c + 3] = __builtin_exp2f((e[c + 3] - m) * LOG2E); s3 += e[c + 3];
    }
    const float sum = (s0 + s1) + (s2 + s3);
    const float inv = 1.f / sum;
    // per-pixel constant for x-recovery: x[c] = ln(s[c]) + M,  M = m + ln(sum)
    const float Mv = fmaf(LN2, __builtin_log2f(sum), m);

    // write s = e*inv as bf16 row [lane][c], swizzled 16B granules
    __bf16* my = &sT[wid][0];
#pragma unroll
    for (int j = 0; j < 8; ++j) {
        bf16x8 v;
#pragma unroll
        for (int i = 0; i < 8; ++i) v[i] = (__bf16)(e[j * 8 + i] * inv);
        const int gr = j ^ (lane & 7);
        *reinterpret_cast<bf16x8*>(my + lane * 64 + gr * 8) = v;
    }
    // wave-local LDS visibility (lockstep lanes); no cross-wave sharing
    asm volatile("s_waitcnt lgkmcnt(0)" ::: "memory");

    const int l15 = lane & 15, lhi = lane >> 4;

    // M[p] for the 4 pixels this lane's epilogue touches (held by lane p)
    float Mp[4];
#pragma unroll
    for (int nt = 0; nt < 4; ++nt)
        Mp[nt] = __shfl(Mv, nt * 16 + l15, 64);

    // ---- phases 2+3 in two d-halves: acc[2][4] keeps VGPR pressure low ----
#pragma unroll
    for (int mtp = 0; mtp < 2; ++mtp) {
        f32x4 acc[2][4] = {};
#pragma unroll
        for (int kt = 0; kt < 2; ++kt) {
            bf16x8 A[2], B[4];
            const __bf16* ab = mixb + (mtp * 32 + l15) * 64 + kt * 32 + lhi * 8;
#pragma unroll
            for (int mt = 0; mt < 2; ++mt)
                A[mt] = *reinterpret_cast<const bf16x8*>(ab + mt * 16 * 64);
#pragma unroll
            for (int nt = 0; nt < 4; ++nt) {
                const int row = nt * 16 + l15;            // pixel
                const int g = (kt * 4 + lhi) ^ (row & 7);
                B[nt] = *reinterpret_cast<const bf16x8*>(my + row * 64 + g * 8);
            }
#pragma unroll
            for (int mt = 0; mt < 2; ++mt)
#pragma unroll
                for (int nt = 0; nt < 4; ++nt)
                    acc[mt][nt] = __builtin_amdgcn_mfma_f32_16x16x32_bf16(
                        A[mt], B[nt], acc[mt][nt], 0, 0, 0);
        }

        // epilogue for d in [mtp*32, mtp*32+32); stores are fire-and-forget
#pragma unroll
        for (int mt = 0; mt < 2; ++mt) {
            const int d0 = mtp * 32 + mt * 16 + lhi * 4;
            const float bb[4] = {bias[d0], bias[d0 + 1], bias[d0 + 2], bias[d0 + 3]};
#pragma unroll
            for (int nt = 0; nt < 4; ++nt) {
                const int p = nt * 16 + l15;
                // s[p][d0..d0+3]: granule (d0>>3)^(p&7), 8B-aligned start
                const int g = ((d0 >> 3) ^ (p & 7));
                const bf16x4 sv = *reinterpret_cast<const bf16x4*>(
                    my + p * 64 + g * 8 + (d0 & 7));
                float* orw = out + ibase + (size_t)d0 * HWSZ + p;
#pragma unroll
                for (int r = 0; r < 4; ++r) {
                    float mixed = acc[mt][nt][r] + bb[r];
                    float act = fmaxf(mixed, 0.2f * mixed);      // RReLU (slope>0)
                    float xv = fmaf(LN2, __builtin_log2f((float)sv[r]), Mp[nt]);
                    float v = fmaf(0.1f, xv, act);
                    orw[(size_t)r * HWSZ] = fmaxf(v, 0.f);
                }
            }
        }
    }
}

extern "C" void kernel_launch(void* const* d_in, const int* in_sizes, int n_in,
                              void* d_out, int out_size, void* d_ws, size_t ws_size,
                              hipStream_t stream) {
    const float* x    = (const float*)d_in[0];
    const float* mix  = (const float*)d_in[1];
    const float* bias = (const float*)d_in[2];
    float* out = (float*)d_out;
    __bf16* mixb = (__bf16*)d_ws;    // 4096 * 2B
    (void)in_sizes; (void)n_in; (void)out_size; (void)ws_size;

    cvt_mix_kernel<<<dim3(16), dim3(256), 0, stream>>>(mix, mixb);
    fused_kernel<<<dim3(4096), dim3(256), 0, stream>>>(x, mixb, bias, out);
}

// Round 11
// 113.386 us; speedup vs baseline: 1.3841x; 1.3841x over previous
//
#include <hip/hip_runtime.h>
#include <math.h>

// (B,C,H,W) = (16,64,256,256)
// out[b,d,hw] = relu( rrelu( sum_c mix[d,c]*softmax_c(x)[b,c,hw] + bias[d] ) + 0.1*x[b,d,hw] )
#define HWSZ 65536

typedef __bf16 bf16x8 __attribute__((ext_vector_type(8)));
typedef __bf16 bf16x4 __attribute__((ext_vector_type(4)));
typedef float f32x4 __attribute__((ext_vector_type(4)));

__global__ __launch_bounds__(256) void cvt_mix_kernel(const float* __restrict__ mix,
                                                      __bf16* __restrict__ mixb) {
    int i = blockIdx.x * 256 + threadIdx.x;   // 4096 elements
    mixb[i] = (__bf16)mix[i];
}

// Exact r4 structure; ONLY change: plain __launch_bounds__(256) (no ",5").
// LDS still caps occupancy at 5 blocks/CU = 20 waves; a ~100-VGPR build keeps
// 5 waves/SIMD, so the bound bought nothing and forced a reload-codegen (VGPR=48).
__global__ __launch_bounds__(256) void fused_kernel(
    const float* __restrict__ x, const __bf16* __restrict__ mixb,
    const float* __restrict__ bias, float* __restrict__ out)
{
    // per-wave 64x64 bf16 s-tile, [pixel][channel], 16B-granule XOR swizzle.
    // Waves never touch each other's slice -> no __syncthreads anywhere.
    __shared__ __bf16 sT[4][64 * 64];
    const int tid  = threadIdx.x;
    const int wid  = tid >> 6;
    const int lane = tid & 63;
    const int waveg = blockIdx.x * 4 + wid;       // 16384 waves
    const int b   = waveg >> 10;
    const int hw0 = (waveg & 1023) << 6;
    const size_t ibase = (size_t)b * (64 * HWSZ) + hw0;

    const float LOG2E = 1.44269504088896340736f;
    const float LN2   = 0.69314718055994530942f;

    // ---- phase 1: channel softmax for pixel hw0+lane ----
    const float* xp = x + ibase + lane;
    float e[64];
#pragma unroll
    for (int c = 0; c < 64; ++c) e[c] = xp[(size_t)c << 16];   // coalesced 256B/instr

    float m0 = e[0], m1 = e[1], m2 = e[2], m3 = e[3];
#pragma unroll
    for (int c = 4; c < 64; c += 4) {
        m0 = fmaxf(m0, e[c]);     m1 = fmaxf(m1, e[c + 1]);
        m2 = fmaxf(m2, e[c + 2]); m3 = fmaxf(m3, e[c + 3]);
    }
    const float m = fmaxf(fmaxf(m0, m1), fmaxf(m2, m3));

    float s0 = 0.f, s1 = 0.f, s2 = 0.f, s3 = 0.f;
#pragma unroll
    for (int c = 0; c < 64; c += 4) {
        e[c]     = __builtin_exp2f((e[c]     - m) * LOG2E); s0 += e[c];
        e[c + 1] = __builtin_exp2f((e[c + 1] - m) * LOG2E); s1 += e[c + 1];
        e[c + 2] = __builtin_exp2f((e[c + 2] - m) * LOG2E); s2 += e[c + 2];
        e[c + 3] = __builtin_exp2f((e[c + 3] - m) * LOG2E); s3 += e[c + 3];
    }
    const float sum = (s0 + s1) + (s2 + s3);
    const float inv = 1.f / sum;
    // per-pixel constant for x-recovery: x[c] = ln(s[c]) + M,  M = m + ln(sum)
    const float Mv = fmaf(LN2, __builtin_log2f(sum), m);

    // write s = e*inv as bf16 row [lane][c], swizzled 16B granules
    __bf16* my = &sT[wid][0];
#pragma unroll
    for (int j = 0; j < 8; ++j) {
        bf16x8 v;
#pragma unroll
        for (int i = 0; i < 8; ++i) v[i] = (__bf16)(e[j * 8 + i] * inv);
        const int gr = j ^ (lane & 7);
        *reinterpret_cast<bf16x8*>(my + lane * 64 + gr * 8) = v;
    }
    // wave-local LDS visibility (lockstep lanes); no cross-wave sharing
    asm volatile("s_waitcnt lgkmcnt(0)" ::: "memory");

    const int l15 = lane & 15, lhi = lane >> 4;

    // M[p] for the 4 pixels this lane's epilogue touches (held by lane p)
    float Mp[4];
#pragma unroll
    for (int nt = 0; nt < 4; ++nt)
        Mp[nt] = __shfl(Mv, nt * 16 + l15, 64);

    // ---- phases 2+3 in two d-halves: acc[2][4] keeps VGPR pressure low ----
#pragma unroll
    for (int mtp = 0; mtp < 2; ++mtp) {
        f32x4 acc[2][4] = {};
#pragma unroll
        for (int kt = 0; kt < 2; ++kt) {
            bf16x8 A[2], B[4];
            const __bf16* ab = mixb + (mtp * 32 + l15) * 64 + kt * 32 + lhi * 8;
#pragma unroll
            for (int mt = 0; mt < 2; ++mt)
                A[mt] = *reinterpret_cast<const bf16x8*>(ab + mt * 16 * 64);
#pragma unroll
            for (int nt = 0; nt < 4; ++nt) {
                const int row = nt * 16 + l15;            // pixel
                const int g = (kt * 4 + lhi) ^ (row & 7);
                B[nt] = *reinterpret_cast<const bf16x8*>(my + row * 64 + g * 8);
            }
#pragma unroll
            for (int mt = 0; mt < 2; ++mt)
#pragma unroll
                for (int nt = 0; nt < 4; ++nt)
                    acc[mt][nt] = __builtin_amdgcn_mfma_f32_16x16x32_bf16(
                        A[mt], B[nt], acc[mt][nt], 0, 0, 0);
        }

        // epilogue for d in [mtp*32, mtp*32+32); stores are fire-and-forget
#pragma unroll
        for (int mt = 0; mt < 2; ++mt) {
            const int d0 = mtp * 32 + mt * 16 + lhi * 4;
            const float bb[4] = {bias[d0], bias[d0 + 1], bias[d0 + 2], bias[d0 + 3]};
#pragma unroll
            for (int nt = 0; nt < 4; ++nt) {
                const int p = nt * 16 + l15;
                // s[p][d0..d0+3]: granule (d0>>3)^(p&7), 8B-aligned start
                const int g = ((d0 >> 3) ^ (p & 7));
                const bf16x4 sv = *reinterpret_cast<const bf16x4*>(
                    my + p * 64 + g * 8 + (d0 & 7));
                float* orw = out + ibase + (size_t)d0 * HWSZ + p;
#pragma unroll
                for (int r = 0; r < 4; ++r) {
                    float mixed = acc[mt][nt][r] + bb[r];
                    float act = fmaxf(mixed, 0.2f * mixed);      // RReLU (slope>0)
                    float xv = fmaf(LN2, __builtin_log2f((float)sv[r]), Mp[nt]);
                    float v = fmaf(0.1f, xv, act);
                    orw[(size_t)r * HWSZ] = fmaxf(v, 0.f);
                }
            }
        }
    }
}

extern "C" void kernel_launch(void* const* d_in, const int* in_sizes, int n_in,
                              void* d_out, int out_size, void* d_ws, size_t ws_size,
                              hipStream_t stream) {
    const float* x    = (const float*)d_in[0];
    const float* mix  = (const float*)d_in[1];
    const float* bias = (const float*)d_in[2];
    float* out = (float*)d_out;
    __bf16* mixb = (__bf16*)d_ws;    // 4096 * 2B
    (void)in_sizes; (void)n_in; (void)out_size; (void)ws_size;

    cvt_mix_kernel<<<dim3(16), dim3(256), 0, stream>>>(mix, mixb);
    fused_kernel<<<dim3(4096), dim3(256), 0, stream>>>(x, mixb, bias, out);
}